// Round 1
// baseline (282.107 us; speedup 1.0000x reference)
//
#include <hip/hip_runtime.h>
#include <hip/hip_bf16.h>

// CTC batch cost forward pass.
// B=1024, T=256, C=128, L=32, S=2L+1=65, blank=C-1=127.
// One block (128 threads) per batch element. Thread s (s<65) owns alpha[s].
// Row of 128 probs staged into LDS coalesced, prefetched 1 step ahead.

#define CTC_B 1024
#define CTC_T 256
#define CTC_C 128
#define CTC_L 32
#define CTC_S 65          // 2*L+1
#define CTC_BLANK 127
#define CTC_NEG_INF (-1e30f)
#define CTC_EPS 1e-7f

__global__ __launch_bounds__(128) void ctc_loss_kernel(
    const int* __restrict__ y_true,   // [B, L] int32
    const float* __restrict__ y_pred, // [B, T, C] float32 (softmax probs)
    float* __restrict__ out)          // [B, 1] float32
{
    const int b = blockIdx.x;
    const int tid = threadIdx.x;
    const int s = tid;  // state index if < CTC_S

    __shared__ float row[CTC_C];          // current timestep's prob row
    __shared__ float alpha_sh[CTC_S + 2]; // [0..1] = padding (states s=-2,-1)

    // padding for shifts (written once; never touched again)
    if (tid < 2) alpha_sh[tid] = CTC_NEG_INF;

    // --- per-state constants: extended label + skip permission ---
    int ext = CTC_BLANK;
    float skip_add = CTC_NEG_INF;
    if (s < CTC_S) {
        if (s & 1) {
            ext = y_true[b * CTC_L + (s >> 1)];
            if (s >= 3) {
                int prev = y_true[b * CTC_L + (s >> 1) - 1];
                if (prev != ext && ext != CTC_BLANK) skip_add = 0.0f;
            }
        }
    }

    const float* yp = y_pred + (size_t)b * CTC_T * CTC_C;

    // --- t = 0: init ---
    row[tid] = yp[tid];
    __syncthreads();
    float alpha = CTC_NEG_INF;
    if (s == 0 || s == 1) {
        alpha = __logf(row[ext] + CTC_EPS);
    }

    // prefetch row for t = 1
    float nxt = yp[CTC_C + tid];

    // --- forward recurrence over t = 1 .. T-1 ---
    for (int t = 1; t < CTC_T; ++t) {
        __syncthreads();  // prior iteration's reads of row/alpha_sh complete
        if (s < CTC_S) alpha_sh[s + 2] = alpha;
        row[tid] = nxt;
        __syncthreads();

        // issue next prefetch early so it overlaps this step's compute
        if (t + 1 < CTC_T) nxt = yp[(t + 1) * CTC_C + tid];

        if (s < CTC_S) {
            float a0 = alpha;                                   // stay
            float a1 = alpha_sh[s + 1];                         // from s-1
            float a2 = alpha_sh[s] + skip_add;                  // from s-2
            a2 = fmaxf(a2, CTC_NEG_INF);
            float m = fmaxf(a0, fmaxf(a1, a2));
            float lse = m + __logf(__expf(a0 - m) + __expf(a1 - m) + __expf(a2 - m));
            float lp = __logf(row[ext] + CTC_EPS);
            alpha = fmaxf(lse + lp, CTC_NEG_INF);
        }
    }

    // --- epilogue: loss = -logaddexp(alpha[S-1], alpha[S-2]) ---
    __syncthreads();
    if (s < CTC_S) alpha_sh[s + 2] = alpha;
    __syncthreads();
    if (tid == 0) {
        float x = alpha_sh[CTC_S + 1];  // s = S-1
        float y = alpha_sh[CTC_S];      // s = S-2
        float m = fmaxf(x, y);
        float r = m + __logf(__expf(x - m) + __expf(y - m));
        out[b] = -r;
    }
}

extern "C" void kernel_launch(void* const* d_in, const int* in_sizes, int n_in,
                              void* d_out, int out_size, void* d_ws, size_t ws_size,
                              hipStream_t stream) {
    const int*   y_true = (const int*)d_in[0];
    const float* y_pred = (const float*)d_in[1];
    float*       out    = (float*)d_out;

    ctc_loss_kernel<<<CTC_B, 128, 0, stream>>>(y_true, y_pred, out);
}